// Round 2
// baseline (398.958 us; speedup 1.0000x reference)
//
#include <hip/hip_runtime.h>
#include <hip/hip_bf16.h>

typedef _Float16 half8 __attribute__((ext_vector_type(8)));
typedef _Float16 half4v __attribute__((ext_vector_type(4)));
typedef float floatx4 __attribute__((ext_vector_type(4)));

#define C_DIM 256
#define M_DIM 512
#define HW 4096
#define TAU 0.0025f

// ---------------- prep: memN = l2norm(relu(relu(mem@w1+b1)@w2+b2)) ----------------
// outputs: mN = fp16 [512][256]; mNt = fp16 transposed [256][512]
__global__ __launch_bounds__(128) void prep_kernel(
    const float* __restrict__ memory, const float* __restrict__ w1,
    const float* __restrict__ b1, const float* __restrict__ w2,
    const float* __restrict__ b2,
    _Float16* __restrict__ mN, _Float16* __restrict__ mNt)
{
  __shared__ float sm[256];
  __shared__ float sh[128];
  __shared__ float s_part[2];
  __shared__ float s_tot;
  const int r = blockIdx.x;
  const int t = threadIdx.x;
  sm[t]       = memory[r * C_DIM + t];
  sm[t + 128] = memory[r * C_DIM + t + 128];
  __syncthreads();
  float acc = b1[t];
#pragma unroll 8
  for (int c = 0; c < 256; ++c) acc = fmaf(sm[c], w1[c * 128 + t], acc);
  sh[t] = fmaxf(acc, 0.f);
  __syncthreads();
  float o0 = b2[t], o1 = b2[t + 128];
#pragma unroll 8
  for (int k = 0; k < 128; ++k) {
    float h = sh[k];
    o0 = fmaf(h, w2[k * 256 + t], o0);
    o1 = fmaf(h, w2[k * 256 + t + 128], o1);
  }
  o0 = fmaxf(o0, 0.f);
  o1 = fmaxf(o1, 0.f);
  float ss = o0 * o0 + o1 * o1;
#pragma unroll
  for (int off = 32; off >= 1; off >>= 1) ss += __shfl_down(ss, off);
  if ((t & 63) == 0) s_part[t >> 6] = ss;
  __syncthreads();
  if (t == 0) s_tot = s_part[0] + s_part[1];
  __syncthreads();
  const float inv = 1.f / fmaxf(sqrtf(s_tot), 1e-12f);
  const float v0 = o0 * inv, v1 = o1 * inv;
  const _Float16 h0 = (_Float16)v0, h1 = (_Float16)v1;
  mN[r * C_DIM + t]         = h0;
  mN[r * C_DIM + t + 128]   = h1;
  mNt[t * M_DIM + r]        = h0;
  mNt[(t + 128) * M_DIM + r] = h1;
}

// ---------------- fused main kernel: 32 pixels per block, 2048 blocks ----------------
// LDS union region (33280 B): Xh[32][264] fp16 -> attb[32][520] fp16 -> Ost[32][260] fp32
__global__ __launch_bounds__(512, 6) void main_kernel(
    const float* __restrict__ x,
    const _Float16* __restrict__ mN,
    const _Float16* __restrict__ mNt,
    float* __restrict__ out, float* __restrict__ attmap)
{
  __shared__ __align__(16) unsigned char smem_u[33280];
  __shared__ float s_red[32][8];
  __shared__ float s_stat[32];
  __shared__ float s_sumsq[32];

  _Float16 (*Xh)[264]   = (_Float16(*)[264])smem_u;
  _Float16 (*attb)[520] = (_Float16(*)[520])smem_u;
  float    (*Ost)[260]  = (float(*)[260])smem_u;

  const int tid  = threadIdx.x;
  const int wave = tid >> 6;     // 0..7
  const int lane = tid & 63;
  const int q    = lane >> 4;    // quad within wave
  const int c16  = lane & 15;
  const int px   = tid & 31;     // pixel for staging phases
  const int cg   = tid >> 5;     // 0..15 channel/slot group

  const int blk = blockIdx.x;          // 2048 blocks
  const int img = blk >> 7;            // 128 blocks per image
  const int hw0 = (blk & 127) * 32;
  const float* __restrict__ xb = x + (size_t)img * C_DIM * HW + hw0;

  if (tid < 32) s_sumsq[tid] = 0.f;
  __syncthreads();  // B0

  // ---- Phase A: load x tile [256ch][32px], fp16 convert, transpose into LDS, sumsq
  float part = 0.f;
#pragma unroll
  for (int i = 0; i < 4; ++i) {
    const int cb = i * 64 + cg * 4;
    const float v0 = xb[(size_t)(cb + 0) * HW + px];
    const float v1 = xb[(size_t)(cb + 1) * HW + px];
    const float v2 = xb[(size_t)(cb + 2) * HW + px];
    const float v3 = xb[(size_t)(cb + 3) * HW + px];
    part += v0 * v0 + v1 * v1 + v2 * v2 + v3 * v3;
    half4v hv = {(_Float16)v0, (_Float16)v1, (_Float16)v2, (_Float16)v3};
    *(half4v*)&Xh[px][cb] = hv;
  }
  atomicAdd(&s_sumsq[px], part);
  __syncthreads();  // B1: Xh + sumsq ready

  // ---- Phase B: GEMM1  S[32][512] = Xh @ mN^T  (fp16 MFMA)
  floatx4 acc[2][4];
#pragma unroll
  for (int mt = 0; mt < 2; ++mt)
#pragma unroll
    for (int nt = 0; nt < 4; ++nt) {
      floatx4 z = {0.f, 0.f, 0.f, 0.f};
      acc[mt][nt] = z;
    }

#pragma unroll
  for (int kb = 0; kb < 8; ++kb) {
    const int k0 = kb * 32 + q * 8;
    half8 ah[2];
#pragma unroll
    for (int mt = 0; mt < 2; ++mt) ah[mt] = *(const half8*)&Xh[mt * 16 + c16][k0];
#pragma unroll
    for (int nt = 0; nt < 4; ++nt) {
      const int n = wave * 64 + nt * 16 + c16;
      const half8 bh = *(const half8*)(mN + (size_t)n * C_DIM + k0);
#pragma unroll
      for (int mt = 0; mt < 2; ++mt)
        acc[mt][nt] = __builtin_amdgcn_mfma_f32_16x16x32_f16(ah[mt], bh, acc[mt][nt], 0, 0, 0);
    }
  }

  // ---- Phase C: scale by 1/||x||, exp (no max needed: logits are cosines in [-1,1]),
  //               softmax-sum, shrink, renorm sum — fp32 in regs
  // C/D layout: value (m = mt*16 + q*4 + r, n = wave*64 + nt*16 + c16)
#pragma unroll
  for (int mt = 0; mt < 2; ++mt)
#pragma unroll
    for (int r = 0; r < 4; ++r) {
      const int m = mt * 16 + q * 4 + r;
      const float iv = 1.f / fmaxf(sqrtf(s_sumsq[m]), 1e-12f);
      float s = 0.f;
#pragma unroll
      for (int nt = 0; nt < 4; ++nt) {
        const float e = __expf(acc[mt][nt][r] * iv);
        acc[mt][nt][r] = e;
        s += e;
      }
      s += __shfl_xor(s, 1);
      s += __shfl_xor(s, 2);
      s += __shfl_xor(s, 4);
      s += __shfl_xor(s, 8);
      if (c16 == 0) s_red[m][wave] = s;
    }
  __syncthreads();  // B2
  if (tid < 32) {
    float v = 0.f;
#pragma unroll
    for (int w = 0; w < 8; ++w) v += s_red[tid][w];
    s_stat[tid] = 1.f / v;
  }
  __syncthreads();  // B3

  // t = relu(p - tau); row sum of t
#pragma unroll
  for (int mt = 0; mt < 2; ++mt)
#pragma unroll
    for (int r = 0; r < 4; ++r) {
      const int m = mt * 16 + q * 4 + r;
      const float isum = s_stat[m];
      float s = 0.f;
#pragma unroll
      for (int nt = 0; nt < 4; ++nt) {
        const float tv = fmaxf(acc[mt][nt][r] * isum - TAU, 0.f);
        acc[mt][nt][r] = tv;
        s += tv;
      }
      s += __shfl_xor(s, 1);
      s += __shfl_xor(s, 2);
      s += __shfl_xor(s, 4);
      s += __shfl_xor(s, 8);
      if (c16 == 0) s_red[m][wave] = s;
    }
  __syncthreads();  // B4  (also: all GEMM1 reads of Xh done -> union reuse safe)
  if (tid < 32) {
    float v = 0.f;
#pragma unroll
    for (int w = 0; w < 8; ++w) v += s_red[tid][w];
    s_stat[tid] = 1.f / fmaxf(v, 1e-12f);
  }
  __syncthreads();  // B5

  // att = t / sumT  -> attb (fp16, union region)
#pragma unroll
  for (int mt = 0; mt < 2; ++mt)
#pragma unroll
    for (int r = 0; r < 4; ++r) {
      const int m = mt * 16 + q * 4 + r;
      const float rs = s_stat[m];
#pragma unroll
      for (int nt = 0; nt < 4; ++nt)
        attb[m][wave * 64 + nt * 16 + c16] = (_Float16)(acc[mt][nt][r] * rs);
    }
  __syncthreads();  // B6: attb ready

  // ---- Phase D: write att_map (coalesced, 32 contiguous px per slot)
#pragma unroll
  for (int i = 0; i < 8; ++i) {
    const int n0 = (cg + 16 * i) * 4;
    const half4v v = *(const half4v*)&attb[px][n0];
    float* dst = attmap + ((size_t)img * M_DIM + n0) * HW + hw0 + px;
    dst[0]            = (float)v[0];
    dst[(size_t)HW]   = (float)v[1];
    dst[(size_t)2*HW] = (float)v[2];
    dst[(size_t)3*HW] = (float)v[3];
  }

  // ---- Phase E: GEMM2  out[32][256] = att @ memN  (fp16)
  floatx4 acc2[2][2];
#pragma unroll
  for (int mt = 0; mt < 2; ++mt)
#pragma unroll
    for (int ct = 0; ct < 2; ++ct) {
      floatx4 z = {0.f, 0.f, 0.f, 0.f};
      acc2[mt][ct] = z;
    }
#pragma unroll
  for (int kb = 0; kb < 16; ++kb) {
    const int k0 = kb * 32 + q * 8;
    half8 a[2];
#pragma unroll
    for (int mt = 0; mt < 2; ++mt) a[mt] = *(const half8*)&attb[mt * 16 + c16][k0];
#pragma unroll
    for (int ct = 0; ct < 2; ++ct) {
      const int cc = wave * 32 + ct * 16 + c16;
      const half8 b = *(const half8*)(mNt + (size_t)cc * M_DIM + k0);
#pragma unroll
      for (int mt = 0; mt < 2; ++mt)
        acc2[mt][ct] = __builtin_amdgcn_mfma_f32_16x16x32_f16(a[mt], b, acc2[mt][ct], 0, 0, 0);
    }
  }
  __syncthreads();  // B7: all attb reads done -> union reuse safe

  // ---- Phase F/G: stage out tile fp32 through LDS (union region), coalesced store
#pragma unroll
  for (int mt = 0; mt < 2; ++mt)
#pragma unroll
    for (int ct = 0; ct < 2; ++ct)
#pragma unroll
      for (int r = 0; r < 4; ++r)
        Ost[mt * 16 + q * 4 + r][wave * 32 + ct * 16 + c16] = acc2[mt][ct][r];
  __syncthreads();  // B8
#pragma unroll
  for (int i = 0; i < 4; ++i) {
    const int c0 = (cg + 16 * i) * 4;
    const floatx4 v = *(const floatx4*)&Ost[px][c0];
    float* dst = out + ((size_t)img * C_DIM + c0) * HW + hw0 + px;
    dst[0]            = v[0];
    dst[(size_t)HW]   = v[1];
    dst[(size_t)2*HW] = v[2];
    dst[(size_t)3*HW] = v[3];
  }
}

extern "C" void kernel_launch(void* const* d_in, const int* in_sizes, int n_in,
                              void* d_out, int out_size, void* d_ws, size_t ws_size,
                              hipStream_t stream) {
  (void)in_sizes; (void)n_in; (void)out_size; (void)ws_size;
  const float* x      = (const float*)d_in[0];
  const float* memory = (const float*)d_in[1];
  const float* w1     = (const float*)d_in[2];
  const float* b1     = (const float*)d_in[3];
  const float* w2     = (const float*)d_in[4];
  const float* b2     = (const float*)d_in[5];
  float* out    = (float*)d_out;
  float* attmap = out + (size_t)16 * C_DIM * HW;  // output first, att_map second

  _Float16* mN  = (_Float16*)d_ws;
  _Float16* mNt = mN + (size_t)M_DIM * C_DIM;

  hipLaunchKernelGGL(prep_kernel, dim3(M_DIM), dim3(128), 0, stream,
                     memory, w1, b1, w2, b2, mN, mNt);
  hipLaunchKernelGGL(main_kernel, dim3(2048), dim3(512), 0, stream,
                     x, mN, mNt, out, attmap);
}

// Round 3
// 380.692 us; speedup vs baseline: 1.0480x; 1.0480x over previous
//
#include <hip/hip_runtime.h>
#include <hip/hip_bf16.h>

typedef _Float16 half8 __attribute__((ext_vector_type(8)));
typedef _Float16 half4v __attribute__((ext_vector_type(4)));
typedef float floatx4 __attribute__((ext_vector_type(4)));

#define C_DIM 256
#define M_DIM 512
#define HW 4096
#define TAU 0.0025f

// ---------------- prep: memN = l2norm(relu(relu(mem@w1+b1)@w2+b2)) ----------------
// outputs: mN = fp16 [512][256]; mNt = fp16 transposed [256][512]
__global__ __launch_bounds__(128) void prep_kernel(
    const float* __restrict__ memory, const float* __restrict__ w1,
    const float* __restrict__ b1, const float* __restrict__ w2,
    const float* __restrict__ b2,
    _Float16* __restrict__ mN, _Float16* __restrict__ mNt)
{
  __shared__ float sm[256];
  __shared__ float sh[128];
  __shared__ float s_part[2];
  __shared__ float s_tot;
  const int r = blockIdx.x;
  const int t = threadIdx.x;
  sm[t]       = memory[r * C_DIM + t];
  sm[t + 128] = memory[r * C_DIM + t + 128];
  __syncthreads();
  float acc = b1[t];
#pragma unroll 8
  for (int c = 0; c < 256; ++c) acc = fmaf(sm[c], w1[c * 128 + t], acc);
  sh[t] = fmaxf(acc, 0.f);
  __syncthreads();
  float o0 = b2[t], o1 = b2[t + 128];
#pragma unroll 8
  for (int k = 0; k < 128; ++k) {
    float h = sh[k];
    o0 = fmaf(h, w2[k * 256 + t], o0);
    o1 = fmaf(h, w2[k * 256 + t + 128], o1);
  }
  o0 = fmaxf(o0, 0.f);
  o1 = fmaxf(o1, 0.f);
  float ss = o0 * o0 + o1 * o1;
#pragma unroll
  for (int off = 32; off >= 1; off >>= 1) ss += __shfl_down(ss, off);
  if ((t & 63) == 0) s_part[t >> 6] = ss;
  __syncthreads();
  if (t == 0) s_tot = s_part[0] + s_part[1];
  __syncthreads();
  const float inv = 1.f / fmaxf(sqrtf(s_tot), 1e-12f);
  const float v0 = o0 * inv, v1 = o1 * inv;
  const _Float16 h0 = (_Float16)v0, h1 = (_Float16)v1;
  mN[r * C_DIM + t]         = h0;
  mN[r * C_DIM + t + 128]   = h1;
  mNt[t * M_DIM + r]        = h0;
  mNt[(t + 128) * M_DIM + r] = h1;
}

#define MFMA16(a, b, c) __builtin_amdgcn_mfma_f32_16x16x32_f16(a, b, c, 0, 0, 0)

// ---------------- fused main kernel: 32 pixels per block, 2048 blocks ----------------
// LDS union region (33280 B): Xh[32][264] fp16 -> attb[32][520] fp16 -> Ost[32][260] fp32
// __launch_bounds__(512,4): 2 blocks/CU (50% occ), 128-VGPR budget for ILP/prefetch.
__global__ __launch_bounds__(512, 4) void main_kernel(
    const float* __restrict__ x,
    const _Float16* __restrict__ mN,
    const _Float16* __restrict__ mNt,
    float* __restrict__ out, float* __restrict__ attmap)
{
  __shared__ __align__(16) unsigned char smem_u[33280];
  __shared__ float s_sumsq[32];
  __shared__ float s_sum1[32];
  __shared__ float s_sum2[32];

  _Float16 (*Xh)[264]   = (_Float16(*)[264])smem_u;
  _Float16 (*attb)[520] = (_Float16(*)[520])smem_u;
  float    (*Ost)[260]  = (float(*)[260])smem_u;

  const int tid  = threadIdx.x;
  const int wave = tid >> 6;     // 0..7
  const int lane = tid & 63;
  const int q    = lane >> 4;    // quad within wave
  const int c16  = lane & 15;
  const int px   = tid & 31;     // pixel for staging phases
  const int cg   = tid >> 5;     // 0..15 channel/slot group
  const int g    = tid >> 3;     // 0..63: channel quad for phase A
  const int pxq  = tid & 7;      // pixel quad for phase A

  const int blk = blockIdx.x;          // 2048 blocks
  const int img = blk >> 7;            // 128 blocks per image
  const int hw0 = (blk & 127) * 32;
  const float* __restrict__ xb = x + (size_t)img * C_DIM * HW + hw0;

  if (tid < 32) { s_sumsq[tid] = 0.f; s_sum1[tid] = 0.f; s_sum2[tid] = 0.f; }
  __syncthreads();  // B0

  // ---- Phase A: float4 loads (4 px x 4 consecutive ch per thread), fp16 pack to LDS,
  //               wave-level sumsq reduction then one atomic per (wave,px)
  {
    floatx4 v[4];
#pragma unroll
    for (int i = 0; i < 4; ++i)
      v[i] = *(const floatx4*)(xb + (size_t)(4 * g + i) * HW + pxq * 4);
    float ps[4];
#pragma unroll
    for (int j = 0; j < 4; ++j) {
      const int p = pxq * 4 + j;
      half4v hv = {(_Float16)v[0][j], (_Float16)v[1][j], (_Float16)v[2][j], (_Float16)v[3][j]};
      *(half4v*)&Xh[p][4 * g] = hv;
      ps[j] = v[0][j] * v[0][j] + v[1][j] * v[1][j] + v[2][j] * v[2][j] + v[3][j] * v[3][j];
    }
    // reduce over the 8 g-values within the wave (lane bits 3..5)
#pragma unroll
    for (int off = 8; off < 64; off <<= 1)
#pragma unroll
      for (int j = 0; j < 4; ++j) ps[j] += __shfl_xor(ps[j], off);
    if ((lane >> 3) == 0) {
#pragma unroll
      for (int j = 0; j < 4; ++j) atomicAdd(&s_sumsq[(lane & 7) * 4 + j], ps[j]);
    }
  }
  __syncthreads();  // B1: Xh + sumsq ready

  // ---- Phase B: GEMM1  S[32][512] = Xh @ mN^T  (fp16 MFMA, 2-stage B prefetch)
  floatx4 acc[2][4];
#pragma unroll
  for (int mt = 0; mt < 2; ++mt)
#pragma unroll
    for (int nt = 0; nt < 4; ++nt) {
      floatx4 z = {0.f, 0.f, 0.f, 0.f};
      acc[mt][nt] = z;
    }
  {
    const _Float16* bp[4];
#pragma unroll
    for (int nt = 0; nt < 4; ++nt)
      bp[nt] = mN + (size_t)(wave * 64 + nt * 16 + c16) * C_DIM + q * 8;
    half8 bcur[4], bnxt[4];
#pragma unroll
    for (int nt = 0; nt < 4; ++nt) bcur[nt] = *(const half8*)bp[nt];
#pragma unroll
    for (int kb = 0; kb < 8; ++kb) {
      if (kb < 7) {
#pragma unroll
        for (int nt = 0; nt < 4; ++nt) bnxt[nt] = *(const half8*)(bp[nt] + (kb + 1) * 32);
      }
      const int k0 = kb * 32 + q * 8;
      const half8 ah0 = *(const half8*)&Xh[c16][k0];
      const half8 ah1 = *(const half8*)&Xh[16 + c16][k0];
#pragma unroll
      for (int nt = 0; nt < 4; ++nt) {
        acc[0][nt] = MFMA16(ah0, bcur[nt], acc[0][nt]);
        acc[1][nt] = MFMA16(ah1, bcur[nt], acc[1][nt]);
      }
#pragma unroll
      for (int nt = 0; nt < 4; ++nt) bcur[nt] = bnxt[nt];
    }
  }

  // ---- Phase C: scale by 1/||x||, exp (cosines in [-1,1], no max shift needed),
  //               single-round reductions via butterfly + LDS atomic
  // C/D layout: value (m = mt*16 + q*4 + r, n = wave*64 + nt*16 + c16)
#pragma unroll
  for (int mt = 0; mt < 2; ++mt)
#pragma unroll
    for (int r = 0; r < 4; ++r) {
      const int m = mt * 16 + q * 4 + r;
      const float iv = 1.f / fmaxf(sqrtf(s_sumsq[m]), 1e-12f);
      float s = 0.f;
#pragma unroll
      for (int nt = 0; nt < 4; ++nt) {
        const float e = __expf(acc[mt][nt][r] * iv);
        acc[mt][nt][r] = e;
        s += e;
      }
      s += __shfl_xor(s, 1);
      s += __shfl_xor(s, 2);
      s += __shfl_xor(s, 4);
      s += __shfl_xor(s, 8);
      if (c16 == 0) atomicAdd(&s_sum1[m], s);
    }
  __syncthreads();  // B2: softmax denominators ready

  // t = relu(p - tau); row sum of t
#pragma unroll
  for (int mt = 0; mt < 2; ++mt)
#pragma unroll
    for (int r = 0; r < 4; ++r) {
      const int m = mt * 16 + q * 4 + r;
      const float isum = 1.f / s_sum1[m];
      float s = 0.f;
#pragma unroll
      for (int nt = 0; nt < 4; ++nt) {
        const float tv = fmaxf(acc[mt][nt][r] * isum - TAU, 0.f);
        acc[mt][nt][r] = tv;
        s += tv;
      }
      s += __shfl_xor(s, 1);
      s += __shfl_xor(s, 2);
      s += __shfl_xor(s, 4);
      s += __shfl_xor(s, 8);
      if (c16 == 0) atomicAdd(&s_sum2[m], s);
    }
  __syncthreads();  // B4: shrink sums ready; all Xh reads done -> union reuse safe

  // att = t / sumT  -> attb (fp16, union region)
#pragma unroll
  for (int mt = 0; mt < 2; ++mt)
#pragma unroll
    for (int r = 0; r < 4; ++r) {
      const int m = mt * 16 + q * 4 + r;
      const float rs = 1.f / fmaxf(s_sum2[m], 1e-12f);
#pragma unroll
      for (int nt = 0; nt < 4; ++nt)
        attb[m][wave * 64 + nt * 16 + c16] = (_Float16)(acc[mt][nt][r] * rs);
    }
  __syncthreads();  // B6: attb ready

  // ---- Phase D: write att_map (coalesced, 32 contiguous px per slot)
#pragma unroll
  for (int i = 0; i < 8; ++i) {
    const int n0 = (cg + 16 * i) * 4;
    const half4v v = *(const half4v*)&attb[px][n0];
    float* dst = attmap + ((size_t)img * M_DIM + n0) * HW + hw0 + px;
    dst[0]            = (float)v[0];
    dst[(size_t)HW]   = (float)v[1];
    dst[(size_t)2*HW] = (float)v[2];
    dst[(size_t)3*HW] = (float)v[3];
  }

  // ---- Phase E: GEMM2  out[32][256] = att @ memN  (fp16, 2-stage B prefetch)
  floatx4 acc2[2][2];
#pragma unroll
  for (int mt = 0; mt < 2; ++mt)
#pragma unroll
    for (int ct = 0; ct < 2; ++ct) {
      floatx4 z = {0.f, 0.f, 0.f, 0.f};
      acc2[mt][ct] = z;
    }
  {
    const _Float16* bp2[2];
#pragma unroll
    for (int ct = 0; ct < 2; ++ct)
      bp2[ct] = mNt + (size_t)(wave * 32 + ct * 16 + c16) * M_DIM + q * 8;
    half8 bcur[2], bnxt[2];
#pragma unroll
    for (int ct = 0; ct < 2; ++ct) bcur[ct] = *(const half8*)bp2[ct];
#pragma unroll
    for (int kb = 0; kb < 16; ++kb) {
      if (kb < 15) {
#pragma unroll
        for (int ct = 0; ct < 2; ++ct) bnxt[ct] = *(const half8*)(bp2[ct] + (kb + 1) * 32);
      }
      const int k0 = kb * 32 + q * 8;
      const half8 a0 = *(const half8*)&attb[c16][k0];
      const half8 a1 = *(const half8*)&attb[16 + c16][k0];
#pragma unroll
      for (int ct = 0; ct < 2; ++ct) {
        acc2[0][ct] = MFMA16(a0, bcur[ct], acc2[0][ct]);
        acc2[1][ct] = MFMA16(a1, bcur[ct], acc2[1][ct]);
      }
#pragma unroll
      for (int ct = 0; ct < 2; ++ct) bcur[ct] = bnxt[ct];
    }
  }
  __syncthreads();  // B7: all attb reads done -> union reuse safe

  // ---- Phase F/G: stage out tile fp32 through LDS (union region), coalesced store
#pragma unroll
  for (int mt = 0; mt < 2; ++mt)
#pragma unroll
    for (int ct = 0; ct < 2; ++ct)
#pragma unroll
      for (int r = 0; r < 4; ++r)
        Ost[mt * 16 + q * 4 + r][wave * 32 + ct * 16 + c16] = acc2[mt][ct][r];
  __syncthreads();  // B8
#pragma unroll
  for (int i = 0; i < 4; ++i) {
    const int c0 = (cg + 16 * i) * 4;
    const floatx4 v = *(const floatx4*)&Ost[px][c0];
    float* dst = out + ((size_t)img * C_DIM + c0) * HW + hw0 + px;
    dst[0]            = v[0];
    dst[(size_t)HW]   = v[1];
    dst[(size_t)2*HW] = v[2];
    dst[(size_t)3*HW] = v[3];
  }
}

extern "C" void kernel_launch(void* const* d_in, const int* in_sizes, int n_in,
                              void* d_out, int out_size, void* d_ws, size_t ws_size,
                              hipStream_t stream) {
  (void)in_sizes; (void)n_in; (void)out_size; (void)ws_size;
  const float* x      = (const float*)d_in[0];
  const float* memory = (const float*)d_in[1];
  const float* w1     = (const float*)d_in[2];
  const float* b1     = (const float*)d_in[3];
  const float* w2     = (const float*)d_in[4];
  const float* b2     = (const float*)d_in[5];
  float* out    = (float*)d_out;
  float* attmap = out + (size_t)16 * C_DIM * HW;  // output first, att_map second

  _Float16* mN  = (_Float16*)d_ws;
  _Float16* mNt = mN + (size_t)M_DIM * C_DIM;

  hipLaunchKernelGGL(prep_kernel, dim3(M_DIM), dim3(128), 0, stream,
                     memory, w1, b1, w2, b2, mN, mNt);
  hipLaunchKernelGGL(main_kernel, dim3(2048), dim3(512), 0, stream,
                     x, mN, mNt, out, attmap);
}

// Round 4
// 336.841 us; speedup vs baseline: 1.1844x; 1.1302x over previous
//
#include <hip/hip_runtime.h>
#include <hip/hip_bf16.h>

typedef _Float16 half8 __attribute__((ext_vector_type(8)));
typedef _Float16 half4v __attribute__((ext_vector_type(4)));
typedef float floatx4 __attribute__((ext_vector_type(4)));

#define C_DIM 256
#define M_DIM 512
#define HW 4096
#define TAU 0.0025f

// ---------------- prep: memN = l2norm(relu(relu(mem@w1+b1)@w2+b2)) ----------------
// outputs: mN = fp16 [512][256]; mNt = fp16 transposed [256][512]
__global__ __launch_bounds__(128) void prep_kernel(
    const float* __restrict__ memory, const float* __restrict__ w1,
    const float* __restrict__ b1, const float* __restrict__ w2,
    const float* __restrict__ b2,
    _Float16* __restrict__ mN, _Float16* __restrict__ mNt)
{
  __shared__ float sm[256];
  __shared__ float sh[128];
  __shared__ float s_part[2];
  __shared__ float s_tot;
  const int r = blockIdx.x;
  const int t = threadIdx.x;
  sm[t]       = memory[r * C_DIM + t];
  sm[t + 128] = memory[r * C_DIM + t + 128];
  __syncthreads();
  float acc = b1[t];
#pragma unroll 8
  for (int c = 0; c < 256; ++c) acc = fmaf(sm[c], w1[c * 128 + t], acc);
  sh[t] = fmaxf(acc, 0.f);
  __syncthreads();
  float o0 = b2[t], o1 = b2[t + 128];
#pragma unroll 8
  for (int k = 0; k < 128; ++k) {
    float h = sh[k];
    o0 = fmaf(h, w2[k * 256 + t], o0);
    o1 = fmaf(h, w2[k * 256 + t + 128], o1);
  }
  o0 = fmaxf(o0, 0.f);
  o1 = fmaxf(o1, 0.f);
  float ss = o0 * o0 + o1 * o1;
#pragma unroll
  for (int off = 32; off >= 1; off >>= 1) ss += __shfl_down(ss, off);
  if ((t & 63) == 0) s_part[t >> 6] = ss;
  __syncthreads();
  if (t == 0) s_tot = s_part[0] + s_part[1];
  __syncthreads();
  const float inv = 1.f / fmaxf(sqrtf(s_tot), 1e-12f);
  const float v0 = o0 * inv, v1 = o1 * inv;
  const _Float16 h0 = (_Float16)v0, h1 = (_Float16)v1;
  mN[r * C_DIM + t]         = h0;
  mN[r * C_DIM + t + 128]   = h1;
  mNt[t * M_DIM + r]        = h0;
  mNt[(t + 128) * M_DIM + r] = h1;
}

#define MFMA16(a, b, c) __builtin_amdgcn_mfma_f32_16x16x32_f16(a, b, c, 0, 0, 0)

// ---------------- fused main kernel: 64 pixels per block, 1024 blocks ----------------
// LDS union (66560 B): Xh[64][264] fp16 -> attb[64][520] fp16 -> Ost[64][260] fp32.
// 67 KB LDS -> 2 blocks/CU is the occupancy ceiling, so the scheduler's VGPR
// target is 128 and it can keep the B-prefetch registers live (the whole point).
__global__ __launch_bounds__(512, 4) void main_kernel(
    const float* __restrict__ x,
    const _Float16* __restrict__ mN,
    const _Float16* __restrict__ mNt,
    float* __restrict__ out, float* __restrict__ attmap)
{
  __shared__ __align__(16) unsigned char smem_u[66560];
  __shared__ float s_sumsq[64];
  __shared__ float s_sum1[64];
  __shared__ float s_sum2[64];

  _Float16 (*Xh)[264]   = (_Float16(*)[264])smem_u;
  _Float16 (*attb)[520] = (_Float16(*)[520])smem_u;
  float    (*Ost)[260]  = (float(*)[260])smem_u;

  const int tid  = threadIdx.x;
  const int wave = tid >> 6;     // 0..7
  const int lane = tid & 63;
  const int q    = lane >> 4;    // quad within wave
  const int c16  = lane & 15;
  const int pxg  = tid & 63;     // pixel for staging phases
  const int sg   = tid >> 6;     // 0..7 slot/channel group for staging phases
  const int g    = tid >> 3;     // 0..63: channel quad for phase A
  const int pxq  = tid & 7;      // pixel quad (with half-loop) for phase A

  const int blk = blockIdx.x;          // 1024 blocks
  const int img = blk >> 6;            // 64 blocks per image
  const int hw0 = (blk & 63) * 64;
  const float* __restrict__ xb = x + (size_t)img * C_DIM * HW + hw0;

  if (tid < 64) { s_sumsq[tid] = 0.f; s_sum1[tid] = 0.f; s_sum2[tid] = 0.f; }
  __syncthreads();  // B0

  // ---- Phase A: float4 loads (2 halves x 4 ch x 4 px per thread), fp16 pack to LDS,
  //               wave-level sumsq reduction then one atomic per (wave,px)
#pragma unroll
  for (int h = 0; h < 2; ++h) {
    floatx4 v[4];
#pragma unroll
    for (int i = 0; i < 4; ++i)
      v[i] = *(const floatx4*)(xb + (size_t)(4 * g + i) * HW + (pxq + 8 * h) * 4);
    float ps[4];
#pragma unroll
    for (int j = 0; j < 4; ++j) {
      const int p = (pxq + 8 * h) * 4 + j;
      half4v hv = {(_Float16)v[0][j], (_Float16)v[1][j], (_Float16)v[2][j], (_Float16)v[3][j]};
      *(half4v*)&Xh[p][4 * g] = hv;
      ps[j] = v[0][j] * v[0][j] + v[1][j] * v[1][j] + v[2][j] * v[2][j] + v[3][j] * v[3][j];
    }
    // reduce over the 8 g-values within the wave (lane bits 3..5)
#pragma unroll
    for (int off = 8; off < 64; off <<= 1)
#pragma unroll
      for (int j = 0; j < 4; ++j) ps[j] += __shfl_xor(ps[j], off);
    if ((lane >> 3) == 0) {
#pragma unroll
      for (int j = 0; j < 4; ++j) atomicAdd(&s_sumsq[4 * (lane & 7) + 32 * h + j], ps[j]);
    }
  }
  __syncthreads();  // B1: Xh + sumsq ready

  // ---- Phase B: GEMM1  S[64][512] = Xh @ mN^T  (fp16 MFMA, 2-stage B prefetch)
  floatx4 acc[4][4];
#pragma unroll
  for (int mt = 0; mt < 4; ++mt)
#pragma unroll
    for (int nt = 0; nt < 4; ++nt) {
      floatx4 z = {0.f, 0.f, 0.f, 0.f};
      acc[mt][nt] = z;
    }
  {
    const _Float16* bp[4];
#pragma unroll
    for (int nt = 0; nt < 4; ++nt)
      bp[nt] = mN + (size_t)(wave * 64 + nt * 16 + c16) * C_DIM + q * 8;
    half8 bcur[4], bnxt[4];
#pragma unroll
    for (int nt = 0; nt < 4; ++nt) bcur[nt] = *(const half8*)bp[nt];
#pragma unroll
    for (int kb = 0; kb < 8; ++kb) {
      if (kb < 7) {
#pragma unroll
        for (int nt = 0; nt < 4; ++nt) bnxt[nt] = *(const half8*)(bp[nt] + (kb + 1) * 32);
      }
      const int k0 = kb * 32 + q * 8;
      half8 ah[4];
#pragma unroll
      for (int mt = 0; mt < 4; ++mt) ah[mt] = *(const half8*)&Xh[mt * 16 + c16][k0];
#pragma unroll
      for (int nt = 0; nt < 4; ++nt)
#pragma unroll
        for (int mt = 0; mt < 4; ++mt)
          acc[mt][nt] = MFMA16(ah[mt], bcur[nt], acc[mt][nt]);
#pragma unroll
      for (int nt = 0; nt < 4; ++nt) bcur[nt] = bnxt[nt];
    }
  }

  // ---- Phase C: scale by 1/||x||, exp (cosines in [-1,1], no max shift needed),
  //               single-round reductions via butterfly + LDS atomic
  // C/D layout: value (m = mt*16 + q*4 + r, n = wave*64 + nt*16 + c16)
#pragma unroll
  for (int mt = 0; mt < 4; ++mt)
#pragma unroll
    for (int r = 0; r < 4; ++r) {
      const int m = mt * 16 + q * 4 + r;
      const float iv = 1.f / fmaxf(sqrtf(s_sumsq[m]), 1e-12f);
      float s = 0.f;
#pragma unroll
      for (int nt = 0; nt < 4; ++nt) {
        const float e = __expf(acc[mt][nt][r] * iv);
        acc[mt][nt][r] = e;
        s += e;
      }
      s += __shfl_xor(s, 1);
      s += __shfl_xor(s, 2);
      s += __shfl_xor(s, 4);
      s += __shfl_xor(s, 8);
      if (c16 == 0) atomicAdd(&s_sum1[m], s);
    }
  __syncthreads();  // B2: softmax denominators ready

  // t = relu(p - tau); row sum of t
#pragma unroll
  for (int mt = 0; mt < 4; ++mt)
#pragma unroll
    for (int r = 0; r < 4; ++r) {
      const int m = mt * 16 + q * 4 + r;
      const float isum = 1.f / s_sum1[m];
      float s = 0.f;
#pragma unroll
      for (int nt = 0; nt < 4; ++nt) {
        const float tv = fmaxf(acc[mt][nt][r] * isum - TAU, 0.f);
        acc[mt][nt][r] = tv;
        s += tv;
      }
      s += __shfl_xor(s, 1);
      s += __shfl_xor(s, 2);
      s += __shfl_xor(s, 4);
      s += __shfl_xor(s, 8);
      if (c16 == 0) atomicAdd(&s_sum2[m], s);
    }
  __syncthreads();  // B3: shrink sums ready; all Xh reads done -> union reuse safe

  // att = t / sumT  -> attb (fp16, union region)
#pragma unroll
  for (int mt = 0; mt < 4; ++mt)
#pragma unroll
    for (int r = 0; r < 4; ++r) {
      const int m = mt * 16 + q * 4 + r;
      const float rs = 1.f / fmaxf(s_sum2[m], 1e-12f);
#pragma unroll
      for (int nt = 0; nt < 4; ++nt)
        attb[m][wave * 64 + nt * 16 + c16] = (_Float16)(acc[mt][nt][r] * rs);
    }
  __syncthreads();  // B4: attb ready

  // ---- Phase D: write att_map (coalesced, 64 contiguous px per slot)
#pragma unroll
  for (int i = 0; i < 16; ++i) {
    const int n0 = (sg + 8 * i) * 4;
    const half4v v = *(const half4v*)&attb[pxg][n0];
    float* dst = attmap + ((size_t)img * M_DIM + n0) * HW + hw0 + pxg;
    dst[0]            = (float)v[0];
    dst[(size_t)HW]   = (float)v[1];
    dst[(size_t)2*HW] = (float)v[2];
    dst[(size_t)3*HW] = (float)v[3];
  }

  // ---- Phase E: GEMM2  out[64][256] = att @ memN  (fp16, 2-stage B prefetch)
  floatx4 acc2[4][2];
#pragma unroll
  for (int mt = 0; mt < 4; ++mt)
#pragma unroll
    for (int ct = 0; ct < 2; ++ct) {
      floatx4 z = {0.f, 0.f, 0.f, 0.f};
      acc2[mt][ct] = z;
    }
  {
    const _Float16* bp2[2];
#pragma unroll
    for (int ct = 0; ct < 2; ++ct)
      bp2[ct] = mNt + (size_t)(wave * 32 + ct * 16 + c16) * M_DIM + q * 8;
    half8 bcur[2], bnxt[2];
#pragma unroll
    for (int ct = 0; ct < 2; ++ct) bcur[ct] = *(const half8*)bp2[ct];
#pragma unroll
    for (int kb = 0; kb < 16; ++kb) {
      if (kb < 15) {
#pragma unroll
        for (int ct = 0; ct < 2; ++ct) bnxt[ct] = *(const half8*)(bp2[ct] + (kb + 1) * 32);
      }
      const int k0 = kb * 32 + q * 8;
      half8 a[4];
#pragma unroll
      for (int mt = 0; mt < 4; ++mt) a[mt] = *(const half8*)&attb[mt * 16 + c16][k0];
#pragma unroll
      for (int ct = 0; ct < 2; ++ct)
#pragma unroll
        for (int mt = 0; mt < 4; ++mt)
          acc2[mt][ct] = MFMA16(a[mt], bcur[ct], acc2[mt][ct]);
#pragma unroll
      for (int ct = 0; ct < 2; ++ct) bcur[ct] = bnxt[ct];
    }
  }
  __syncthreads();  // B5: all attb reads done -> union reuse safe

  // ---- Phase F/G: stage out tile fp32 through LDS (union region), coalesced store
#pragma unroll
  for (int mt = 0; mt < 4; ++mt)
#pragma unroll
    for (int ct = 0; ct < 2; ++ct)
#pragma unroll
      for (int r = 0; r < 4; ++r)
        Ost[mt * 16 + q * 4 + r][wave * 32 + ct * 16 + c16] = acc2[mt][ct][r];
  __syncthreads();  // B6
#pragma unroll
  for (int i = 0; i < 8; ++i) {
    const int c0 = (sg + 8 * i) * 4;
    const floatx4 v = *(const floatx4*)&Ost[pxg][c0];
    float* dst = out + ((size_t)img * C_DIM + c0) * HW + hw0 + pxg;
    dst[0]            = v[0];
    dst[(size_t)HW]   = v[1];
    dst[(size_t)2*HW] = v[2];
    dst[(size_t)3*HW] = v[3];
  }
}

extern "C" void kernel_launch(void* const* d_in, const int* in_sizes, int n_in,
                              void* d_out, int out_size, void* d_ws, size_t ws_size,
                              hipStream_t stream) {
  (void)in_sizes; (void)n_in; (void)out_size; (void)ws_size;
  const float* x      = (const float*)d_in[0];
  const float* memory = (const float*)d_in[1];
  const float* w1     = (const float*)d_in[2];
  const float* b1     = (const float*)d_in[3];
  const float* w2     = (const float*)d_in[4];
  const float* b2     = (const float*)d_in[5];
  float* out    = (float*)d_out;
  float* attmap = out + (size_t)16 * C_DIM * HW;  // output first, att_map second

  _Float16* mN  = (_Float16*)d_ws;
  _Float16* mNt = mN + (size_t)M_DIM * C_DIM;

  hipLaunchKernelGGL(prep_kernel, dim3(M_DIM), dim3(128), 0, stream,
                     memory, w1, b1, w2, b2, mN, mNt);
  hipLaunchKernelGGL(main_kernel, dim3(1024), dim3(512), 0, stream,
                     x, mN, mNt, out, attmap);
}